// Round 7
// baseline (158.788 us; speedup 1.0000x reference)
//
#include <hip/hip_runtime.h>
#include <hip/hip_bf16.h>

// Causal MHA: B=4,N=4,L=1024,H=8,E=64, fp32 in/out, bf16 MFMA compute.
// X[b,n,l,h,e] flat = ((bn*L + l)*H + h)*E + e ; head=(bn,h), 128 heads.
//
// ROUND-7: equal-weight blocks via ANTI-DIAGONAL q assignment. R6 measured
// 26% occupancy with all pipes ~25%: block weights 4qt+4 in {4..16} make
// per-CU makespan = max(weight) -> cross-CU tail + intra-pair tail. Here
// wave w of block c owns q rows w*128 + c*32 .. +31 (one 32-row slice from
// each of the 8 q-bands), so EVERY block spans s-tiles 0..15 and weighs
// exactly 16 units: identical makespan, zero cross-CU tail. Within a block
// the active-wave count ramps 8 -> 2 over s; odd-c blocks iterate s
// DESCENDING (fixed-max softmax is order-invariant, o/lsum are additive) so
// an asc+desc pair co-resident on a CU holds ~10-11 active waves constant.
// Grid/threads unchanged from R6 (512 blocks x 512 thr); head = blk&127
// keeps a head's 4 blocks on one XCD for K/V L2 reuse.
//
// Diff vs PASSING R6 kept minimal (R5 lesson): qrow formula, ntiles=16,
// stile asc/desc mapping + signed prefetch step. Inner compute, staging
// maps, swizzles, barrier protocol, epilogue byte-identical.
//
// NO __launch_bounds__ min-waves hint: rounds 1 & 3 proved the allocator
// over-shrinks and spills 12-16 dwords/thread (+16-24 MB HBM writes).
//
// Kept verified machinery: transposed S^T = K.Q^T (operand swap), P kept in
// registers and redistributed with v_permlane32/16_swap into K=32 B-frags
// (K=16 mfma costs the same cycles as K=32 -- never use it for bulk FLOPs),
// XOR-swizzled K/V LDS (conflicts = 0 measured), double-buffered with a
// single lgkm-only barrier per iteration (vmcnt never drained at barriers),
// diag mask only on the relq==0 / relq==-32 sub-tiles, fixed-max softmax,
// scale*log2e folded into Q fragments.

typedef __bf16 bf16x8 __attribute__((ext_vector_type(8)));
typedef __bf16 bf16x4 __attribute__((ext_vector_type(4)));
typedef float  f32x4  __attribute__((ext_vector_type(4)));
typedef unsigned u32x2 __attribute__((ext_vector_type(2)));
typedef unsigned u32x4 __attribute__((ext_vector_type(4)));

#define SEQ 1024
#define ROWSTRIDE 512 // H*E

__device__ inline bf16x8 pack8(float4 a, float4 b) {
    bf16x8 f;
    f[0]=(__bf16)a.x; f[1]=(__bf16)a.y; f[2]=(__bf16)a.z; f[3]=(__bf16)a.w;
    f[4]=(__bf16)b.x; f[5]=(__bf16)b.y; f[6]=(__bf16)b.z; f[7]=(__bf16)b.w;
    return f;
}

__device__ inline bf16x8 pack8s(float4 a, float4 b, float s) {
    bf16x8 f;
    f[0]=(__bf16)(a.x*s); f[1]=(__bf16)(a.y*s); f[2]=(__bf16)(a.z*s); f[3]=(__bf16)(a.w*s);
    f[4]=(__bf16)(b.x*s); f[5]=(__bf16)(b.y*s); f[6]=(__bf16)(b.z*s); f[7]=(__bf16)(b.w*s);
    return f;
}

// LDS-visibility-only barrier: do NOT drain vmcnt (keeps global prefetch
// loads in flight; compiler inserts vmcnt waits at register use).
__device__ inline void lds_barrier() {
    asm volatile("s_waitcnt lgkmcnt(0)\n\ts_barrier" ::: "memory");
}

// gfx950 two-output lane swaps; both operands are modified.
__device__ inline void swap32(unsigned &a, unsigned &b) {
    asm("v_permlane32_swap_b32 %0, %1" : "+v"(a), "+v"(b));
}
__device__ inline void swap16(unsigned &a, unsigned &b) {
    asm("v_permlane16_swap_b32 %0, %1" : "+v"(a), "+v"(b));
}

// exp2 + optional causal mask + pack + cross-quad redistribute for one
// (q-group, s-half). Input: sA/sB = S^T c-tiles cl=0/1 (lane: q=l15,
// s_loc = cl*16 + quad*4 + r). Output: B-frag of 16x16x32 holding
// P[s_loc = quad*8 + j] for q = l15. Masked lanes: s_loc > qloc when diag.
__device__ inline bf16x8 softmax_pack(f32x4 sA, f32x4 sB, bool diag,
                                      int qloc, int quad, float &ls)
{
    unsigned U0a, U0b, U1a, U1b;
    {
        bf16x4 pk;
        #pragma unroll
        for (int r = 0; r < 4; ++r) {
            float p = __builtin_amdgcn_exp2f(sA[r]);
            p = (diag && (quad * 4 + r > qloc)) ? 0.f : p;
            ls += p; pk[r] = (__bf16)p;
        }
        u32x2 uu = __builtin_bit_cast(u32x2, pk);
        U0a = uu[0]; U0b = uu[1];
    }
    {
        bf16x4 pk;
        #pragma unroll
        for (int r = 0; r < 4; ++r) {
            float p = __builtin_amdgcn_exp2f(sB[r]);
            p = (diag && (16 + quad * 4 + r > qloc)) ? 0.f : p;
            ls += p; pk[r] = (__bf16)p;
        }
        u32x2 uu = __builtin_bit_cast(u32x2, pk);
        U1a = uu[0]; U1b = uu[1];
    }
    // lane holds s=16cl+4*quad+r -> frag needs s=8*quad+j
    swap32(U0a, U1a); swap32(U0b, U1b);
    swap16(U0a, U1a); swap16(U0b, U1b);
    u32x4 w; w[0] = U0a; w[1] = U0b; w[2] = U1a; w[3] = U1b;
    return __builtin_bit_cast(bf16x8, w);
}

__global__ __launch_bounds__(512) void attn_fwd(
    const float* __restrict__ Qg,
    const float* __restrict__ Kg,
    const float* __restrict__ Vg,
    float* __restrict__ Og)
{
    // double-buffered, XOR-swizzled (16B blocks): phys_blk = blk ^ (row&7)
    __shared__ __bf16 Kds[2][64][64];   // Kds[buf][s][e]
    __shared__ __bf16 Vds[2][64][64];   // transposed: Vds[buf][e][s]

    const int blk  = blockIdx.x;
    const int head = blk & 127;
    const int h    = head & 7;
    const int bn   = head >> 3;
    const int c    = blk >> 7;          // head-local block 0..3 (q-band slice)
    const bool desc = (c & 1);          // odd slices iterate s descending

    const int tid  = threadIdx.x;
    const int wave = tid >> 6;          // 0..7
    const int lane = tid & 63;
    const int quad = lane >> 4;
    const int l15  = lane & 15;
    const int swz  = l15 & 7;           // read-side row-xor ((x*16+l15)&7 == l15&7)

    const size_t base = (size_t)bn * SEQ * ROWSTRIDE + (size_t)h * 64;

    // scale * log2(e), folded into Q fragment
    const float kscale = 0.125f * 1.44269504088896f;

    // ---- Q fragments, B-operand layout of 16x16x32 (n=l15 -> q row, k=quad*8+j)
    // anti-diagonal: wave w owns q rows [w*128 + c*32, +32) -> every block
    // holds one slice of every q-band -> all blocks weigh 16 s-tiles.
    const int qrow = wave * 128 + c * 32;
    bf16x8 qa[2][2];                          // [qh][t]
    #pragma unroll
    for (int qh = 0; qh < 2; ++qh) {
        const float* qp = Qg + base + (size_t)(qrow + qh * 16 + l15) * ROWSTRIDE + quad * 8;
        #pragma unroll
        for (int t = 0; t < 2; ++t)
            qa[qh][t] = pack8s(*(const float4*)(qp + t * 32),
                               *(const float4*)(qp + t * 32 + 4), kscale);
    }

    f32x4 o[2][4];        // O^T accumulators [qh][etile]; lane: q=l15, e=et*16+quad*4+r
    float lsum0 = 0.f, lsum1 = 0.f;
    #pragma unroll
    for (int qh = 0; qh < 2; ++qh)
        #pragma unroll
        for (int e = 0; e < 4; ++e) o[qh][e] = (f32x4){0.f, 0.f, 0.f, 0.f};

    // K staging: thread -> row sr (0..63), 16B-block kc (0..7): 8 floats each
    const int sr = tid >> 3, kc = tid & 7;
    // V staging: thread -> e-column ve, 8 s-rows from wave*8 (free transpose)
    const int ve = tid & 63;

    // s-tile traversal: asc 0..15 or desc 15..0; all 16 always staged.
    const int stile0 = desc ? 15 : 0;
    const ptrdiff_t step = (desc ? -(ptrdiff_t)1 : (ptrdiff_t)1) * 64 * ROWSTRIDE;

    const float* kp = Kg + base + (size_t)(stile0 * 64 + sr) * ROWSTRIDE + kc * 8;
    const float* vp = Vg + base + (size_t)(stile0 * 64 + wave * 8) * ROWSTRIDE + ve;

    // ---- prefetch first tile into registers
    float4 kpre[2];
    float  vpre[8];
    kpre[0] = *(const float4*)kp;
    kpre[1] = *(const float4*)(kp + 4);
    #pragma unroll
    for (int j = 0; j < 8; ++j) vpre[j] = vp[(size_t)j * ROWSTRIDE];
    kp += step;
    vp += step;

    for (int tile = 0; tile < 16; ++tile) {
        const int bb = tile & 1;
        const int stile = desc ? (15 - tile) : tile;

        // ---- commit prefetched K/V to LDS buf[bb] (bf16, swizzled b128 writes).
        // Reads of buf[bb] were lgkm-drained at the previous barrier.
        *(bf16x8*)&Kds[bb][sr][(kc ^ (sr & 7)) << 3] = pack8(kpre[0], kpre[1]);
        {
            bf16x8 f0;
            #pragma unroll
            for (int jj = 0; jj < 8; ++jj) f0[jj] = (__bf16)vpre[jj];
            *(bf16x8*)&Vds[bb][ve][(wave ^ (ve & 7)) << 3] = f0;
        }

        // ---- issue prefetch for next tile (in flight through barrier+compute)
        if (tile + 1 < 16) {
            kpre[0] = *(const float4*)kp;
            kpre[1] = *(const float4*)(kp + 4);
            #pragma unroll
            for (int j = 0; j < 8; ++j) vpre[j] = vp[(size_t)j * ROWSTRIDE];
            kp += step;
            vp += step;
        }

        lds_barrier();   // single barrier per iteration: buf[bb] visible (lgkm only)

        // wave-uniform causal state: relq = s0 - qrow (multiple of 32).
        const int relq = stile * 64 - qrow;
        const bool active   = relq < 32;   // some s in this tile is needed
        const bool hiActive = relq < 0;    // upper 32 s rows not fully masked

        // P B-frags, named + zero-init (no runtime indexing, no undef paths):
        // pfQH_T holds P[s = T*32 + quad*8 + j] for q-group QH.
        bf16x8 pf00 = {}, pf01 = {}, pf10 = {}, pf11 = {};

        if (active) {
            // ======== phase 0: s rows 0..31 of this tile ========
            {
                f32x4 s00 = (f32x4){0.f,0.f,0.f,0.f}, s01 = (f32x4){0.f,0.f,0.f,0.f};
                f32x4 s10 = (f32x4){0.f,0.f,0.f,0.f}, s11 = (f32x4){0.f,0.f,0.f,0.f};
                __builtin_amdgcn_s_setprio(1);
                #pragma unroll
                for (int t = 0; t < 2; ++t) {
                    bf16x8 kb0 = *(const bf16x8*)&Kds[bb][ 0 + l15][((t * 4 + quad) ^ swz) << 3];
                    bf16x8 kb1 = *(const bf16x8*)&Kds[bb][16 + l15][((t * 4 + quad) ^ swz) << 3];
                    // operand swap: A=K, B=Q -> D = S^T; each kb feeds both qh
                    s00 = __builtin_amdgcn_mfma_f32_16x16x32_bf16(kb0, qa[0][t], s00, 0, 0, 0);
                    s10 = __builtin_amdgcn_mfma_f32_16x16x32_bf16(kb0, qa[1][t], s10, 0, 0, 0);
                    s01 = __builtin_amdgcn_mfma_f32_16x16x32_bf16(kb1, qa[0][t], s01, 0, 0, 0);
                    s11 = __builtin_amdgcn_mfma_f32_16x16x32_bf16(kb1, qa[1][t], s11, 0, 0, 0);
                }
                __builtin_amdgcn_s_setprio(0);
                const bool diag0 = (relq == 0);
                pf00 = softmax_pack(s00, s01, diag0, l15,      quad, lsum0);
                pf10 = softmax_pack(s10, s11, diag0, 16 + l15, quad, lsum1);
            }
            // ======== phase 1: s rows 32..63 of this tile ========
            if (hiActive) {
                f32x4 s00 = (f32x4){0.f,0.f,0.f,0.f}, s01 = (f32x4){0.f,0.f,0.f,0.f};
                f32x4 s10 = (f32x4){0.f,0.f,0.f,0.f}, s11 = (f32x4){0.f,0.f,0.f,0.f};
                __builtin_amdgcn_s_setprio(1);
                #pragma unroll
                for (int t = 0; t < 2; ++t) {
                    bf16x8 kb0 = *(const bf16x8*)&Kds[bb][32 + l15][((t * 4 + quad) ^ swz) << 3];
                    bf16x8 kb1 = *(const bf16x8*)&Kds[bb][48 + l15][((t * 4 + quad) ^ swz) << 3];
                    s00 = __builtin_amdgcn_mfma_f32_16x16x32_bf16(kb0, qa[0][t], s00, 0, 0, 0);
                    s10 = __builtin_amdgcn_mfma_f32_16x16x32_bf16(kb0, qa[1][t], s10, 0, 0, 0);
                    s01 = __builtin_amdgcn_mfma_f32_16x16x32_bf16(kb1, qa[0][t], s01, 0, 0, 0);
                    s11 = __builtin_amdgcn_mfma_f32_16x16x32_bf16(kb1, qa[1][t], s11, 0, 0, 0);
                }
                __builtin_amdgcn_s_setprio(0);
                const bool diag1 = (relq == -32);
                pf01 = softmax_pack(s00, s01, diag1, l15,      quad, lsum0);
                pf11 = softmax_pack(s10, s11, diag1, 16 + l15, quad, lsum1);
            }

            // ======== PV: O^T += V^T.P^T, K=32 MFMA; each vb feeds both qh ====
            __builtin_amdgcn_s_setprio(1);
            #pragma unroll
            for (int e = 0; e < 4; ++e) {
                bf16x8 vb0 = *(const bf16x8*)&Vds[bb][e * 16 + l15][(quad ^ swz) << 3];
                o[0][e] = __builtin_amdgcn_mfma_f32_16x16x32_bf16(vb0, pf00, o[0][e], 0, 0, 0);
                o[1][e] = __builtin_amdgcn_mfma_f32_16x16x32_bf16(vb0, pf10, o[1][e], 0, 0, 0);
                if (hiActive) {
                    bf16x8 vb1 = *(const bf16x8*)&Vds[bb][e * 16 + l15][((4 + quad) ^ swz) << 3];
                    o[0][e] = __builtin_amdgcn_mfma_f32_16x16x32_bf16(vb1, pf01, o[0][e], 0, 0, 0);
                    o[1][e] = __builtin_amdgcn_mfma_f32_16x16x32_bf16(vb1, pf11, o[1][e], 0, 0, 0);
                }
            }
            __builtin_amdgcn_s_setprio(0);
        }
    }

    // ---- epilogue: reduce l across quads (lane owns q=l15), O/l, float4 store
    #pragma unroll
    for (int qh = 0; qh < 2; ++qh) {
        float s = qh ? lsum1 : lsum0;
        s += __shfl_xor(s, 16);
        s += __shfl_xor(s, 32);
        const float inv_l = 1.f / s;
        float* op = Og + base + (size_t)(qrow + qh * 16 + l15) * ROWSTRIDE + quad * 4;
        #pragma unroll
        for (int e = 0; e < 4; ++e) {
            float4 v;
            v.x = o[qh][e][0] * inv_l;
            v.y = o[qh][e][1] * inv_l;
            v.z = o[qh][e][2] * inv_l;
            v.w = o[qh][e][3] * inv_l;
            *(float4*)(op + e * 16) = v;
        }
    }
}

extern "C" void kernel_launch(void* const* d_in, const int* in_sizes, int n_in,
                              void* d_out, int out_size, void* d_ws, size_t ws_size,
                              hipStream_t stream) {
    const float* Qg = (const float*)d_in[0];
    const float* Kg = (const float*)d_in[1];
    const float* Vg = (const float*)d_in[2];
    float* Og = (float*)d_out;
    // 128 heads x 4 anti-diagonal slices = 512 blocks, 512 threads.
    // Every block = exactly 16 s-tile iterations (equal weight).
    attn_fwd<<<dim3(512), dim3(512), 0, stream>>>(Qg, Kg, Vg, Og);
}

// Round 8
// 149.878 us; speedup vs baseline: 1.0594x; 1.0594x over previous
//
#include <hip/hip_runtime.h>
#include <hip/hip_bf16.h>

// Causal MHA: B=4,N=4,L=1024,H=8,E=64, fp32 in/out, bf16 MFMA compute.
// X[b,n,l,h,e] flat = ((bn*L + l)*H + h)*E + e ; head=(bn,h), 128 heads.
//
// ROUND-8 = R6 (best, 51.5us) + 2-DEEP register prefetch.
// R7's controlled experiment measured the marginal cost of one staging-
// barrier iteration: ~2600 cycles (dur tracked per-CU staging iterations,
// not occupancy). The excess over its ~400cy compute content is the
// unhidden vmcnt wait at commit: 1-deep prefetch gives a load less than one
// iteration (<~900cy HBM latency) to land. Here commit(t) consumes registers
// issued at t-2 (>=2 iterations ~3-5k cy in flight) -> compiler's counted
// s_waitcnt vmcnt(N) at commit finds the data already landed.
// Two NAMED buffer sets (A/B) rotate; loop body written twice per iteration
// (bb and all register indices compile-time -- rule #20 / R5 lesson: no
// runtime-indexed register arrays, no lambdas over hot state).
// ntiles = 4qt+4 is always even -> clean 2-step loop.
//
// Everything else byte-identical to passing R6:
//  - 512 threads / 8 waves; block covers 256 contiguous q rows (32 q/wave);
//    40 stagings/head; complementary-weight dispatch (qt = blk<256 ? blk>>7
//    : 3-((blk&255)>>7)) -> co-resident pairs weigh 4+16 / 8+12 = 20/CU;
//    head = blk&127 keeps a head's blocks on one XCD.
//  - transposed S^T = K.Q^T (operand swap); P stays in registers,
//    redistributed with v_permlane32/16_swap into K=32 B-frags (K=16 mfma
//    costs the same cycles as K=32 -- never use it for bulk FLOPs);
//  - XOR-swizzled K/V LDS (conflicts = 0 measured), double-buffered, single
//    lgkm-only barrier per iteration (vmcnt never drained at barriers);
//  - diag mask only on the relq==0 / relq==-32 sub-tiles; fixed-max softmax;
//    scale*log2e folded into Q fragments.
//  - NO __launch_bounds__ min-waves hint (rounds 1 & 3: allocator
//    over-shrinks and spills 12-16 dwords/thread into the main loop).

typedef __bf16 bf16x8 __attribute__((ext_vector_type(8)));
typedef __bf16 bf16x4 __attribute__((ext_vector_type(4)));
typedef float  f32x4  __attribute__((ext_vector_type(4)));
typedef unsigned u32x2 __attribute__((ext_vector_type(2)));
typedef unsigned u32x4 __attribute__((ext_vector_type(4)));

#define SEQ 1024
#define ROWSTRIDE 512 // H*E

__device__ inline bf16x8 pack8(float4 a, float4 b) {
    bf16x8 f;
    f[0]=(__bf16)a.x; f[1]=(__bf16)a.y; f[2]=(__bf16)a.z; f[3]=(__bf16)a.w;
    f[4]=(__bf16)b.x; f[5]=(__bf16)b.y; f[6]=(__bf16)b.z; f[7]=(__bf16)b.w;
    return f;
}

__device__ inline bf16x8 pack8s(float4 a, float4 b, float s) {
    bf16x8 f;
    f[0]=(__bf16)(a.x*s); f[1]=(__bf16)(a.y*s); f[2]=(__bf16)(a.z*s); f[3]=(__bf16)(a.w*s);
    f[4]=(__bf16)(b.x*s); f[5]=(__bf16)(b.y*s); f[6]=(__bf16)(b.z*s); f[7]=(__bf16)(b.w*s);
    return f;
}

// LDS-visibility-only barrier: do NOT drain vmcnt (keeps global prefetch
// loads in flight; compiler inserts vmcnt waits at register use).
__device__ inline void lds_barrier() {
    asm volatile("s_waitcnt lgkmcnt(0)\n\ts_barrier" ::: "memory");
}

// gfx950 two-output lane swaps; both operands are modified.
__device__ inline void swap32(unsigned &a, unsigned &b) {
    asm("v_permlane32_swap_b32 %0, %1" : "+v"(a), "+v"(b));
}
__device__ inline void swap16(unsigned &a, unsigned &b) {
    asm("v_permlane16_swap_b32 %0, %1" : "+v"(a), "+v"(b));
}

// exp2 + optional causal mask + pack + cross-quad redistribute for one
// (q-group, s-half). Input: sA/sB = S^T c-tiles cl=0/1 (lane: q=l15,
// s_loc = cl*16 + quad*4 + r). Output: B-frag of 16x16x32 holding
// P[s_loc = quad*8 + j] for q = l15. Masked lanes: s_loc > qloc when diag.
__device__ inline bf16x8 softmax_pack(f32x4 sA, f32x4 sB, bool diag,
                                      int qloc, int quad, float &ls)
{
    unsigned U0a, U0b, U1a, U1b;
    {
        bf16x4 pk;
        #pragma unroll
        for (int r = 0; r < 4; ++r) {
            float p = __builtin_amdgcn_exp2f(sA[r]);
            p = (diag && (quad * 4 + r > qloc)) ? 0.f : p;
            ls += p; pk[r] = (__bf16)p;
        }
        u32x2 uu = __builtin_bit_cast(u32x2, pk);
        U0a = uu[0]; U0b = uu[1];
    }
    {
        bf16x4 pk;
        #pragma unroll
        for (int r = 0; r < 4; ++r) {
            float p = __builtin_amdgcn_exp2f(sB[r]);
            p = (diag && (16 + quad * 4 + r > qloc)) ? 0.f : p;
            ls += p; pk[r] = (__bf16)p;
        }
        u32x2 uu = __builtin_bit_cast(u32x2, pk);
        U1a = uu[0]; U1b = uu[1];
    }
    // lane holds s=16cl+4*quad+r -> frag needs s=8*quad+j
    swap32(U0a, U1a); swap32(U0b, U1b);
    swap16(U0a, U1a); swap16(U0b, U1b);
    u32x4 w; w[0] = U0a; w[1] = U0b; w[2] = U1a; w[3] = U1b;
    return __builtin_bit_cast(bf16x8, w);
}

// ---- one staging+compute iteration; BB and register names compile-time ----
#define LOAD_TILE(KARR, VARR)                                                  \
    {                                                                          \
        KARR[0] = *(const float4*)kp;                                          \
        KARR[1] = *(const float4*)(kp + 4);                                    \
        _Pragma("unroll")                                                      \
        for (int j = 0; j < 8; ++j) VARR[j] = vp[(size_t)j * ROWSTRIDE];       \
        kp += (size_t)64 * ROWSTRIDE;                                          \
        vp += (size_t)64 * ROWSTRIDE;                                          \
    }

#define BODY(TILE, BB, KARR, VARR)                                             \
    {                                                                          \
        const int tile_ = (TILE);                                              \
        /* commit prefetched K/V (issued 2 iterations ago) to LDS buf[BB] */   \
        *(bf16x8*)&Kds[BB][sr][(kc ^ (sr & 7)) << 3] = pack8(KARR[0], KARR[1]);\
        {                                                                      \
            bf16x8 f0_;                                                        \
            _Pragma("unroll")                                                  \
            for (int jj = 0; jj < 8; ++jj) f0_[jj] = (__bf16)VARR[jj];         \
            *(bf16x8*)&Vds[BB][ve][(wave ^ (ve & 7)) << 3] = f0_;              \
        }                                                                      \
        /* refill the just-freed buffer with tile_+2 (2 iterations ahead) */   \
        if (tile_ + 2 < ntiles) LOAD_TILE(KARR, VARR)                          \
        lds_barrier();                                                         \
        const int relq = tile_ * 64 - qrow;                                    \
        const bool active   = relq < 32;                                       \
        const bool hiActive = relq < 0;                                        \
        bf16x8 pf00 = {}, pf01 = {}, pf10 = {}, pf11 = {};                     \
        if (active) {                                                          \
            { /* phase 0: s rows 0..31 */                                      \
                f32x4 s00 = (f32x4){0.f,0.f,0.f,0.f}, s01 = (f32x4){0.f,0.f,0.f,0.f}; \
                f32x4 s10 = (f32x4){0.f,0.f,0.f,0.f}, s11 = (f32x4){0.f,0.f,0.f,0.f}; \
                __builtin_amdgcn_s_setprio(1);                                 \
                _Pragma("unroll")                                              \
                for (int t = 0; t < 2; ++t) {                                  \
                    bf16x8 kb0 = *(const bf16x8*)&Kds[BB][ 0 + l15][((t * 4 + quad) ^ swz) << 3]; \
                    bf16x8 kb1 = *(const bf16x8*)&Kds[BB][16 + l15][((t * 4 + quad) ^ swz) << 3]; \
                    s00 = __builtin_amdgcn_mfma_f32_16x16x32_bf16(kb0, qa[0][t], s00, 0, 0, 0); \
                    s10 = __builtin_amdgcn_mfma_f32_16x16x32_bf16(kb0, qa[1][t], s10, 0, 0, 0); \
                    s01 = __builtin_amdgcn_mfma_f32_16x16x32_bf16(kb1, qa[0][t], s01, 0, 0, 0); \
                    s11 = __builtin_amdgcn_mfma_f32_16x16x32_bf16(kb1, qa[1][t], s11, 0, 0, 0); \
                }                                                              \
                __builtin_amdgcn_s_setprio(0);                                 \
                const bool diag0 = (relq == 0);                                \
                pf00 = softmax_pack(s00, s01, diag0, l15,      quad, lsum0);   \
                pf10 = softmax_pack(s10, s11, diag0, 16 + l15, quad, lsum1);   \
            }                                                                  \
            if (hiActive) { /* phase 1: s rows 32..63 */                       \
                f32x4 s00 = (f32x4){0.f,0.f,0.f,0.f}, s01 = (f32x4){0.f,0.f,0.f,0.f}; \
                f32x4 s10 = (f32x4){0.f,0.f,0.f,0.f}, s11 = (f32x4){0.f,0.f,0.f,0.f}; \
                __builtin_amdgcn_s_setprio(1);                                 \
                _Pragma("unroll")                                              \
                for (int t = 0; t < 2; ++t) {                                  \
                    bf16x8 kb0 = *(const bf16x8*)&Kds[BB][32 + l15][((t * 4 + quad) ^ swz) << 3]; \
                    bf16x8 kb1 = *(const bf16x8*)&Kds[BB][48 + l15][((t * 4 + quad) ^ swz) << 3]; \
                    s00 = __builtin_amdgcn_mfma_f32_16x16x32_bf16(kb0, qa[0][t], s00, 0, 0, 0); \
                    s10 = __builtin_amdgcn_mfma_f32_16x16x32_bf16(kb0, qa[1][t], s10, 0, 0, 0); \
                    s01 = __builtin_amdgcn_mfma_f32_16x16x32_bf16(kb1, qa[0][t], s01, 0, 0, 0); \
                    s11 = __builtin_amdgcn_mfma_f32_16x16x32_bf16(kb1, qa[1][t], s11, 0, 0, 0); \
                }                                                              \
                __builtin_amdgcn_s_setprio(0);                                 \
                const bool diag1 = (relq == -32);                              \
                pf01 = softmax_pack(s00, s01, diag1, l15,      quad, lsum0);   \
                pf11 = softmax_pack(s10, s11, diag1, 16 + l15, quad, lsum1);   \
            }                                                                  \
            /* PV: O^T += V^T.P^T, K=32 MFMA; each vb feeds both qh */         \
            __builtin_amdgcn_s_setprio(1);                                     \
            _Pragma("unroll")                                                  \
            for (int e = 0; e < 4; ++e) {                                      \
                bf16x8 vb0 = *(const bf16x8*)&Vds[BB][e * 16 + l15][(quad ^ swz) << 3]; \
                o[0][e] = __builtin_amdgcn_mfma_f32_16x16x32_bf16(vb0, pf00, o[0][e], 0, 0, 0); \
                o[1][e] = __builtin_amdgcn_mfma_f32_16x16x32_bf16(vb0, pf10, o[1][e], 0, 0, 0); \
                if (hiActive) {                                                \
                    bf16x8 vb1 = *(const bf16x8*)&Vds[BB][e * 16 + l15][((4 + quad) ^ swz) << 3]; \
                    o[0][e] = __builtin_amdgcn_mfma_f32_16x16x32_bf16(vb1, pf01, o[0][e], 0, 0, 0); \
                    o[1][e] = __builtin_amdgcn_mfma_f32_16x16x32_bf16(vb1, pf11, o[1][e], 0, 0, 0); \
                }                                                              \
            }                                                                  \
            __builtin_amdgcn_s_setprio(0);                                     \
        }                                                                      \
    }

__global__ __launch_bounds__(512) void attn_fwd(
    const float* __restrict__ Qg,
    const float* __restrict__ Kg,
    const float* __restrict__ Vg,
    float* __restrict__ Og)
{
    // double-buffered, XOR-swizzled (16B blocks): phys_blk = blk ^ (row&7)
    __shared__ __bf16 Kds[2][64][64];   // Kds[buf][s][e]
    __shared__ __bf16 Vds[2][64][64];   // transposed: Vds[buf][e][s]

    const int blk  = blockIdx.x;
    const int head = blk & 127;
    const int h    = head & 7;
    const int bn   = head >> 3;
    // complementary-weight pairing for co-resident blocks (c, c+256):
    // qt in {0,1} for blk<256, {3,2} for blk>=256 -> per-CU weight ~20 units
    const int qt   = (blk < 256) ? (blk >> 7) : (3 - ((blk & 255) >> 7));

    const int tid  = threadIdx.x;
    const int wave = tid >> 6;          // 0..7
    const int lane = tid & 63;
    const int quad = lane >> 4;
    const int l15  = lane & 15;
    const int swz  = l15 & 7;           // read-side row-xor ((x*16+l15)&7 == l15&7)

    const size_t base = (size_t)bn * SEQ * ROWSTRIDE + (size_t)h * 64;

    // scale * log2(e), folded into Q fragment
    const float kscale = 0.125f * 1.44269504088896f;

    // ---- Q fragments, B-operand layout of 16x16x32 (n=l15 -> q row, k=quad*8+j)
    const int qrow = qt * 256 + wave * 32;   // wave owns q rows [qrow, qrow+32)
    bf16x8 qa[2][2];                          // [qh][t]
    #pragma unroll
    for (int qh = 0; qh < 2; ++qh) {
        const float* qp = Qg + base + (size_t)(qrow + qh * 16 + l15) * ROWSTRIDE + quad * 8;
        #pragma unroll
        for (int t = 0; t < 2; ++t)
            qa[qh][t] = pack8s(*(const float4*)(qp + t * 32),
                               *(const float4*)(qp + t * 32 + 4), kscale);
    }

    f32x4 o[2][4];        // O^T accumulators [qh][etile]; lane: q=l15, e=et*16+quad*4+r
    float lsum0 = 0.f, lsum1 = 0.f;
    #pragma unroll
    for (int qh = 0; qh < 2; ++qh)
        #pragma unroll
        for (int e = 0; e < 4; ++e) o[qh][e] = (f32x4){0.f, 0.f, 0.f, 0.f};

    // K staging: thread -> row sr (0..63), 16B-block kc (0..7): 8 floats each
    const int sr = tid >> 3, kc = tid & 7;
    // V staging: thread -> e-column ve, 8 s-rows from wave*8 (free transpose)
    const int ve = tid & 63;

    const int ntiles = 4 * qt + 4;      // always even, >= 4

    const float* kp = Kg + base + (size_t)sr * ROWSTRIDE + kc * 8;
    const float* vp = Vg + base + (size_t)(wave * 8) * ROWSTRIDE + ve;

    // ---- 2-deep prologue: tiles 0 -> A, 1 -> B
    float4 kA[2], kB[2];
    float  vA[8], vB[8];
    LOAD_TILE(kA, vA)
    LOAD_TILE(kB, vB)

    const int nt2 = ntiles >> 1;
    for (int t2 = 0; t2 < nt2; ++t2) {
        BODY(2 * t2,     0, kA, vA)
        BODY(2 * t2 + 1, 1, kB, vB)
    }

    // ---- epilogue: reduce l across quads (lane owns q=l15), O/l, float4 store
    #pragma unroll
    for (int qh = 0; qh < 2; ++qh) {
        float s = qh ? lsum1 : lsum0;
        s += __shfl_xor(s, 16);
        s += __shfl_xor(s, 32);
        const float inv_l = 1.f / s;
        float* op = Og + base + (size_t)(qrow + qh * 16 + l15) * ROWSTRIDE + quad * 4;
        #pragma unroll
        for (int e = 0; e < 4; ++e) {
            float4 v;
            v.x = o[qh][e][0] * inv_l;
            v.y = o[qh][e][1] * inv_l;
            v.z = o[qh][e][2] * inv_l;
            v.w = o[qh][e][3] * inv_l;
            *(float4*)(op + e * 16) = v;
        }
    }
}

extern "C" void kernel_launch(void* const* d_in, const int* in_sizes, int n_in,
                              void* d_out, int out_size, void* d_ws, size_t ws_size,
                              hipStream_t stream) {
    const float* Qg = (const float*)d_in[0];
    const float* Kg = (const float*)d_in[1];
    const float* Vg = (const float*)d_in[2];
    float* Og = (float*)d_out;
    // 128 heads x 4 q-ranges (256 q rows each) = 512 blocks, 512 threads.
    attn_fwd<<<dim3(512), dim3(512), 0, stream>>>(Qg, Kg, Vg, Og);
}